// Round 2
// baseline (312.223 us; speedup 1.0000x reference)
//
#include <hip/hip_runtime.h>
#include <cstdint>

// LSTM cell: B=8192, DIM_IN=1024, DIM_OUT=1024, d=2048
// gates = [X|H][8192,2048] @ W[2048,4096] + b ; epilogue fused into GEMM.
// R3: 32x32x16 MFMA (17% less matrix-pipe time), 2 barriers/K-tile with
// 16-MFMA clusters, counted vmcnt(4) (drain only in peeled last tile),
// XOR-swizzled LDS (chunk ^= (row>>1)&3, pre-swizzled global sources),
// setprio, bijective XCD swizzle, preps merged into one launch.
// W pre-permuted: n'' = (j>>5)*128 + g*32 + (j&31) so each wave's 128
// n''-cols = 32 j-cols x 4 gates, one gate per 32x32 N-frag.

#define B_ROWS 8192
#define DK 2048
#define DOUT 1024
#define BM 256
#define BN 256
#define BK 64
#define NKT (DK / BK)   // 32 K-tiles

typedef __bf16 bf16x8 __attribute__((ext_vector_type(8)));
typedef __bf16 bf16x4 __attribute__((ext_vector_type(4)));
typedef float f32x16 __attribute__((ext_vector_type(16)));

__device__ inline void load16_to_lds(const __bf16* gsrc, __bf16* ldst) {
    __builtin_amdgcn_global_load_lds(
        (const __attribute__((address_space(1))) void*)gsrc,
        (__attribute__((address_space(3))) void*)ldst,
        16, 0, 0);
}

// sigmoid(x) = 1/(1+2^(-x*log2e)); tanh(x) = 1 - 2/(1+2^(2x*log2e))
__device__ inline float fast_sigmoid(float x) {
    return __builtin_amdgcn_rcpf(1.0f + __builtin_amdgcn_exp2f(-1.442695041f * x));
}
__device__ inline float fast_tanh(float x) {
    return 1.0f - 2.0f * __builtin_amdgcn_rcpf(1.0f + __builtin_amdgcn_exp2f(2.885390082f * x));
}

// ---- merged prep: blocks 0..2047 permute W, blocks 2048.. convert X ----
// prep_w part: Wt[n''][k] = bf16(W_g[k][j]); n'' = (j>>5)*128 + g*32 + (j&31)
// prep_x part: X = bf16(concat(x,h)) [8192][2048] row-major
__global__ __launch_bounds__(256) void prep_all(
    const float* __restrict__ x, const float* __restrict__ h,
    __bf16* __restrict__ X,
    const float* __restrict__ WI, const float* __restrict__ WF,
    const float* __restrict__ WG, const float* __restrict__ WO,
    __bf16* __restrict__ Wt)
{
    __shared__ float t[32][33];
    if (blockIdx.x >= 2048) {
        int id = (blockIdx.x - 2048) * 256 + threadIdx.x;
        int b = id >> 9;
        int k = (id & 511) * 4;
        float4 v;
        if (k < 1024) v = *(const float4*)&x[(size_t)b * 1024 + k];
        else          v = *(const float4*)&h[(size_t)b * 1024 + (k - 1024)];
        bf16x4 o = { (__bf16)v.x, (__bf16)v.y, (__bf16)v.z, (__bf16)v.w };
        *(bf16x4*)&X[(size_t)b * 2048 + k] = o;
        return;
    }
    int kb = blockIdx.x & 63;      // 0..63  (k tiles of 32)
    int jb = blockIdx.x >> 6;      // 0..31  (j tiles of 32)
    int j0 = jb * 32;
    int tx = threadIdx.x & 31, ty = threadIdx.x >> 5;   // logical (32,8)
    const float* Ws[4] = {WI, WF, WG, WO};
#pragma unroll
    for (int g = 0; g < 4; ++g) {
        const float* W = Ws[g];
#pragma unroll
        for (int yy = 0; yy < 32; yy += 8) {
            int k = kb * 32 + ty + yy;
            t[ty + yy][tx] = W[(size_t)k * 1024 + j0 + tx];
        }
        __syncthreads();
#pragma unroll
        for (int yy = 0; yy < 32; yy += 8) {
            int r = ty + yy;                  // jlo within this 32-col group
            int npp = jb * 128 + g * 32 + r;
            Wt[(size_t)npp * 2048 + kb * 32 + tx] = (__bf16)t[tx][r];
        }
        __syncthreads();
    }
}

// ---- fused GEMM + LSTM epilogue, 256^2, 32x32x16, 2 barriers/tile ----
__global__ __launch_bounds__(512, 2) void lstm_gemm(
    const __bf16* __restrict__ Xbf, const __bf16* __restrict__ Wt,
    const float* __restrict__ c,
    const float* __restrict__ bI, const float* __restrict__ bF,
    const float* __restrict__ bG, const float* __restrict__ bO,
    float* __restrict__ outH, float* __restrict__ outC)
{
    // [dbuf][A=0/B=1][khalf][256 rows x 32 cols bf16] = 8 x 16KB = 128KB
    __shared__ __bf16 lds[2][2][2][8192];

    const int tid  = threadIdx.x;
    const int lane = tid & 63;
    const int wave = tid >> 6;
    const int wm = wave >> 1;          // 0..3 : 64-row slice
    const int wn = wave & 1;           // 0..1 : 128-col (n'') slice

    // bijective XCD swizzle (512 % 8 == 0): XCD x gets ids x*64..x*64+63
    // -> nb in {2x,2x+1}: one B-panel L2-resident per XCD round.
    const int bid = blockIdx.x;
    const int id  = (bid & 7) * 64 + (bid >> 3);
    const int mb = id & 31;
    const int nb = id >> 5;
    const int m0 = mb * BM;
    const int n0 = nb * BN;

    // ---- staging: linear LDS dest, pre-swizzled global source ----
    // unit = [256][32] bf16 = 16KB; thread covers bytes o0 and o0+8192.
    // physical chunk pk at (row,pk) holds logical chunk pk ^ ((row>>1)&3).
    const int o0  = wave * 1024 + lane * 16;
    const int r0  = o0 >> 6;
    const int lc0 = ((o0 >> 4) & 3) ^ ((r0 >> 1) & 3);
    const __bf16* gA0 = Xbf + (size_t)(m0 + r0)       * DK + lc0 * 8;
    const __bf16* gA1 = Xbf + (size_t)(m0 + r0 + 128) * DK + lc0 * 8;
    const __bf16* gB0 = Wt  + (size_t)(n0 + r0)       * DK + lc0 * 8;
    const __bf16* gB1 = Wt  + (size_t)(n0 + r0 + 128) * DK + lc0 * 8;
    const int ls0 = wave * 512;        // element offset in unit
    const int ls1 = ls0 + 4096;

    // ---- swizzled ds_read offsets (element, within a unit) ----
    // A frag: row = wm*64 + mi*32 + (lane&31); k-chunk = (lane>>5) + ks*2
    // B frag: row = wn*128 + nf*32 + (lane&31) (nf = gate)
    const int lr = lane & 31;
    const int kq = lane >> 5;
    int aoff[2][2], boff[4][2];
#pragma unroll
    for (int mi = 0; mi < 2; ++mi) {
        int row = wm * 64 + mi * 32 + lr;
#pragma unroll
        for (int ks = 0; ks < 2; ++ks) {
            int pc = (kq + ks * 2) ^ ((row >> 1) & 3);
            aoff[mi][ks] = row * 32 + pc * 8;
        }
    }
#pragma unroll
    for (int nf = 0; nf < 4; ++nf) {
        int row = wn * 128 + nf * 32 + lr;
#pragma unroll
        for (int ks = 0; ks < 2; ++ks) {
            int pc = (kq + ks * 2) ^ ((row >> 1) & 3);
            boff[nf][ks] = row * 32 + pc * 8;
        }
    }

    f32x16 acc[2][4];
#pragma unroll
    for (int mi = 0; mi < 2; ++mi)
#pragma unroll
        for (int nf = 0; nf < 4; ++nf)
#pragma unroll
            for (int e = 0; e < 16; ++e) acc[mi][nf][e] = 0.f;

#define STAGE_A(d_, kh_, ko_) do { \
    load16_to_lds(gA0 + (ko_) + (kh_) * 32, &lds[d_][0][kh_][ls0]); \
    load16_to_lds(gA1 + (ko_) + (kh_) * 32, &lds[d_][0][kh_][ls1]); } while (0)
#define STAGE_B(d_, kh_, ko_) do { \
    load16_to_lds(gB0 + (ko_) + (kh_) * 32, &lds[d_][1][kh_][ls0]); \
    load16_to_lds(gB1 + (ko_) + (kh_) * 32, &lds[d_][1][kh_][ls1]); } while (0)

// One phase = one kh-half of one K-tile: wait, barrier, 12 ds_reads,
// stage next tile's matching unit (4 loads), 16 MFMAs.
// Steady state: 8 loads outstanding at phase top; vmcnt(4) -> the oldest
// 4 (exactly the unit consumed here) have landed.
#define PHASE(d_, dn_, kh_, ko_, vm_, st_) do { \
    asm volatile("s_waitcnt " vm_ " lgkmcnt(0)" ::: "memory"); \
    __builtin_amdgcn_s_barrier(); \
    asm volatile("" ::: "memory"); \
    bf16x8 a0_  = *(const bf16x8*)&lds[d_][0][kh_][aoff[0][0]]; \
    bf16x8 b0_  = *(const bf16x8*)&lds[d_][1][kh_][boff[0][0]]; \
    bf16x8 b1_  = *(const bf16x8*)&lds[d_][1][kh_][boff[1][0]]; \
    bf16x8 b2_  = *(const bf16x8*)&lds[d_][1][kh_][boff[2][0]]; \
    bf16x8 b3_  = *(const bf16x8*)&lds[d_][1][kh_][boff[3][0]]; \
    bf16x8 a1_  = *(const bf16x8*)&lds[d_][0][kh_][aoff[1][0]]; \
    bf16x8 a0k_ = *(const bf16x8*)&lds[d_][0][kh_][aoff[0][1]]; \
    bf16x8 b0k_ = *(const bf16x8*)&lds[d_][1][kh_][boff[0][1]]; \
    bf16x8 b1k_ = *(const bf16x8*)&lds[d_][1][kh_][boff[1][1]]; \
    bf16x8 b2k_ = *(const bf16x8*)&lds[d_][1][kh_][boff[2][1]]; \
    bf16x8 b3k_ = *(const bf16x8*)&lds[d_][1][kh_][boff[3][1]]; \
    bf16x8 a1k_ = *(const bf16x8*)&lds[d_][0][kh_][aoff[1][1]]; \
    if (st_) { STAGE_A(dn_, kh_, ko_); STAGE_B(dn_, kh_, ko_); } \
    __builtin_amdgcn_s_setprio(1); \
    acc[0][0] = __builtin_amdgcn_mfma_f32_32x32x16_bf16(a0_, b0_, acc[0][0], 0, 0, 0); \
    acc[0][1] = __builtin_amdgcn_mfma_f32_32x32x16_bf16(a0_, b1_, acc[0][1], 0, 0, 0); \
    acc[0][2] = __builtin_amdgcn_mfma_f32_32x32x16_bf16(a0_, b2_, acc[0][2], 0, 0, 0); \
    acc[0][3] = __builtin_amdgcn_mfma_f32_32x32x16_bf16(a0_, b3_, acc[0][3], 0, 0, 0); \
    acc[1][0] = __builtin_amdgcn_mfma_f32_32x32x16_bf16(a1_, b0_, acc[1][0], 0, 0, 0); \
    acc[1][1] = __builtin_amdgcn_mfma_f32_32x32x16_bf16(a1_, b1_, acc[1][1], 0, 0, 0); \
    acc[1][2] = __builtin_amdgcn_mfma_f32_32x32x16_bf16(a1_, b2_, acc[1][2], 0, 0, 0); \
    acc[1][3] = __builtin_amdgcn_mfma_f32_32x32x16_bf16(a1_, b3_, acc[1][3], 0, 0, 0); \
    acc[0][0] = __builtin_amdgcn_mfma_f32_32x32x16_bf16(a0k_, b0k_, acc[0][0], 0, 0, 0); \
    acc[0][1] = __builtin_amdgcn_mfma_f32_32x32x16_bf16(a0k_, b1k_, acc[0][1], 0, 0, 0); \
    acc[0][2] = __builtin_amdgcn_mfma_f32_32x32x16_bf16(a0k_, b2k_, acc[0][2], 0, 0, 0); \
    acc[0][3] = __builtin_amdgcn_mfma_f32_32x32x16_bf16(a0k_, b3k_, acc[0][3], 0, 0, 0); \
    acc[1][0] = __builtin_amdgcn_mfma_f32_32x32x16_bf16(a1k_, b0k_, acc[1][0], 0, 0, 0); \
    acc[1][1] = __builtin_amdgcn_mfma_f32_32x32x16_bf16(a1k_, b1k_, acc[1][1], 0, 0, 0); \
    acc[1][2] = __builtin_amdgcn_mfma_f32_32x32x16_bf16(a1k_, b2k_, acc[1][2], 0, 0, 0); \
    acc[1][3] = __builtin_amdgcn_mfma_f32_32x32x16_bf16(a1k_, b3k_, acc[1][3], 0, 0, 0); \
    __builtin_amdgcn_s_setprio(0); \
} while (0)

    // prologue: stage tile 0's 4 units in consumption order (8 loads)
    STAGE_A(0, 0, 0);
    STAGE_B(0, 0, 0);
    STAGE_A(0, 1, 0);
    STAGE_B(0, 1, 0);

    // tiles 0..29: uniform (d = t&1 via explicit pair unroll)
    for (int t = 0; t < NKT - 2; t += 2) {
        const int ko0 = (t + 1) * BK;
        const int ko1 = (t + 2) * BK;
        PHASE(0, 1, 0, ko0, "vmcnt(4)", 1);
        PHASE(0, 1, 1, ko0, "vmcnt(4)", 1);
        PHASE(1, 0, 0, ko1, "vmcnt(4)", 1);
        PHASE(1, 0, 1, ko1, "vmcnt(4)", 1);
    }
    // tile 30: stages tile 31
    PHASE(0, 1, 0, (NKT - 1) * BK, "vmcnt(4)", 1);
    PHASE(0, 1, 1, (NKT - 1) * BK, "vmcnt(4)", 1);
    // tile 31: no stage; drain counted 4 -> 0
    PHASE(1, 0, 0, 0, "vmcnt(4)", 0);
    PHASE(1, 0, 1, 0, "vmcnt(0)", 0);

#undef PHASE
#undef STAGE_A
#undef STAGE_B

    // epilogue: 32x32 C/D layout col=lane&31, row=(reg&3)+8*(reg>>2)+4*(lane>>5)
    // acc[mi][g] = gate g at j = (nb*2+wn)*32 + (lane&31)
    const int j = (nb * 2 + wn) * 32 + lr;
    const float biI = bI[j], biF = bF[j], biG = bG[j], biO = bO[j];
    const int rb = m0 + wm * 64 + 4 * kq;
#pragma unroll
    for (int mi = 0; mi < 2; ++mi) {
#pragma unroll
        for (int rg = 0; rg < 16; ++rg) {
            int row = rb + mi * 32 + (rg & 3) + 8 * (rg >> 2);
            float I = fast_sigmoid(acc[mi][0][rg] + biI);
            float F = fast_sigmoid(acc[mi][1][rg] + biF);
            float G = fast_tanh(acc[mi][2][rg] + biG);
            float O = fast_sigmoid(acc[mi][3][rg] + biO);
            size_t idx = (size_t)row * DOUT + j;
            float Cn = F * c[idx] + I * G;
            outH[idx] = O * fast_tanh(Cn);
            outC[idx] = Cn;
        }
    }
}

extern "C" void kernel_launch(void* const* d_in, const int* in_sizes, int n_in,
                              void* d_out, int out_size, void* d_ws, size_t ws_size,
                              hipStream_t stream) {
    const float* x  = (const float*)d_in[0];
    const float* h  = (const float*)d_in[1];
    const float* c  = (const float*)d_in[2];
    const float* WI = (const float*)d_in[3];
    const float* bI = (const float*)d_in[4];
    const float* WF = (const float*)d_in[5];
    const float* bF = (const float*)d_in[6];
    const float* WG = (const float*)d_in[7];
    const float* bG = (const float*)d_in[8];
    const float* WO = (const float*)d_in[9];
    const float* bO = (const float*)d_in[10];

    __bf16* Xbf = (__bf16*)d_ws;                                    // 32 MB
    __bf16* Wt  = (__bf16*)((char*)d_ws + (size_t)B_ROWS * DK * 2); // 16 MB
    float* outH = (float*)d_out;
    float* outC = outH + (size_t)B_ROWS * DOUT;

    // blocks 0..2047: W permute+cast; blocks 2048..18431: X concat+cast
    prep_all<<<2048 + (B_ROWS * DK / 4) / 256, 256, 0, stream>>>(
        x, h, Xbf, WI, WF, WG, WO, Wt);
    lstm_gemm<<<dim3((B_ROWS / BM) * (4 * DOUT / BN)), dim3(512), 0, stream>>>(
        Xbf, Wt, c, bI, bF, bG, bO, outH, outC);
}